// Round 6
// baseline (2591.070 us; speedup 1.0000x reference)
//
#include <hip/hip_runtime.h>
#include <stdint.h>

#define Bsz 256
#define Tt  128
#define INs 256
#define Hh  512

typedef __attribute__((ext_vector_type(8))) short short8;
typedef __attribute__((ext_vector_type(4))) float f32x4;

__device__ __forceinline__ unsigned short f2bf(float f) {
  union { float f; unsigned int u; } v; v.f = f;
  unsigned int u = v.u;
  u += 0x7FFFu + ((u >> 16) & 1u);   // round-to-nearest-even
  return (unsigned short)(u >> 16);
}
__device__ __forceinline__ float bf2f(unsigned short h) {
  union { unsigned int u; float f; } v; v.u = ((unsigned int)h) << 16;
  return v.f;
}
__device__ __forceinline__ float sigf(float x) { return 1.0f / (1.0f + expf(-x)); }

#define AL(P) __hip_atomic_load((P), __ATOMIC_RELAXED, __HIP_MEMORY_SCOPE_AGENT)

union Q2S { unsigned long long q[2]; short8 s; };

// ---- ws layout (bytes) ----
#define WS_FLAGS 0
#define WS_H0    16384
#define WS_H1    (WS_H0 + 2 * Bsz * Hh * 2)
#define WS_ZERO_BYTES (WS_H1 + 2 * Bsz * Hh * 2)   // 1065088

#define GL_STRIDE 65
#define W_BYTES   131072
#define GL_BYTES  (64 * GL_STRIDE * 4)             // 16640
#define BW_OFF    (W_BYTES + GL_BYTES)
#define DYN_SHMEM (BW_OFF + 64 * 4 + 48 * 4)       // 148160

#define MFMA4(A0, A1, B0, B1)                                                   \
  acc00 = __builtin_amdgcn_mfma_f32_16x16x32_bf16(A0, B0, acc00, 0, 0, 0);      \
  acc01 = __builtin_amdgcn_mfma_f32_16x16x32_bf16(A0, B1, acc01, 0, 0, 0);      \
  acc10 = __builtin_amdgcn_mfma_f32_16x16x32_bf16(A1, B0, acc10, 0, 0, 0);      \
  acc11 = __builtin_amdgcn_mfma_f32_16x16x32_bf16(A1, B1, acc11, 0, 0, 0);

// 4-deep prefetch pipeline over 16 ksteps of coherent h loads.
// PA/PB: row-block base pointers; KB: kstep base in LDS B layout.
#define H_GEMM_HALF(PA, PB, KB)                                                 \
  {                                                                             \
    unsigned long long pq[16];                                                  \
    _Pragma("unroll")                                                           \
    for (int s = 0; s < 4; ++s) {                                               \
      const unsigned long long* qa = (const unsigned long long*)((PA) + s * 32);\
      const unsigned long long* qb = (const unsigned long long*)((PB) + s * 32);\
      pq[s * 4 + 0] = AL(qa); pq[s * 4 + 1] = AL(qa + 1);                       \
      pq[s * 4 + 2] = AL(qb); pq[s * 4 + 3] = AL(qb + 1);                       \
    }                                                                           \
    _Pragma("unroll")                                                           \
    for (int ks = 0; ks < 16; ++ks) {                                           \
      const int sl = (ks & 3) << 2;                                             \
      Q2S ua, ub;                                                               \
      ua.q[0] = pq[sl + 0]; ua.q[1] = pq[sl + 1];                               \
      ub.q[0] = pq[sl + 2]; ub.q[1] = pq[sl + 3];                               \
      if (ks < 12) {                                                            \
        const unsigned long long* qa =                                          \
            (const unsigned long long*)((PA) + (ks + 4) * 32);                  \
        const unsigned long long* qb =                                          \
            (const unsigned long long*)((PB) + (ks + 4) * 32);                  \
        pq[sl + 0] = AL(qa); pq[sl + 1] = AL(qa + 1);                           \
        pq[sl + 2] = AL(qb); pq[sl + 3] = AL(qb + 1);                           \
      }                                                                         \
      const char* bb = smem + ((((ks + (KB)) << 2) + (wn << 1)) * 64 + lane) * 16; \
      short8 b0v = *(const short8*)bb;                                          \
      short8 b1v = *(const short8*)(bb + 1024);                                 \
      MFMA4(ua.s, ub.s, b0v, b1v)                                               \
    }                                                                           \
  }

extern "C" __global__ void __launch_bounds__(256)
lstm_fused(const float* __restrict__ x,
           const float* __restrict__ Wx0, const float* __restrict__ bx0,
           const float* __restrict__ Wh0, const float* __restrict__ Wc0,
           const float* __restrict__ Wx1, const float* __restrict__ bx1,
           const float* __restrict__ Wh1, const float* __restrict__ Wc1,
           const float* __restrict__ Wfc, const float* __restrict__ bfc,
           float* __restrict__ out, unsigned char* __restrict__ ws)
{
  extern __shared__ char smem[];
  unsigned int*   flg = (unsigned int*)(ws + WS_FLAGS);
  unsigned short* h0b = (unsigned short*)(ws + WS_H0);
  unsigned short* h1b = (unsigned short*)(ws + WS_H1);
  float* gl  = (float*)(smem + W_BYTES);
  float* bxl = (float*)(smem + BW_OFF);        // 64 floats: bias per local gate-col
  float* wcl = bxl + 64;                       // 48 floats: peephole weights

  const int wg    = blockIdx.x;
  const int rb    = wg >> 6;        // batch-row group (0..3), 64 rows each
  const int sub   = wg & 63;
  const int layer = sub >> 5;
  const int cb    = sub & 31;
  const int tid   = threadIdx.x;
  const int lane  = tid & 63;
  const int wave  = tid >> 6;
  const int wm    = wave >> 1, wn = wave & 1;
  const int j0    = cb << 4;

  // ---- preload this WG's weight slice into LDS, bf16, fragment order ----
  {
    const int K   = layer ? 1024 : 768;
    const int k8s = K >> 3;
    const int ng  = 64 * k8s;
    for (int idx = tid; idx < ng; idx += 256) {
      const int nl = idx / k8s;
      const int k8 = idx - nl * k8s;
      const int k  = k8 << 3;
      const int nrow = (nl >> 4) * Hh + j0 + (nl & 15);
      const float* src;
      if (!layer) src = (k < INs) ? (Wx0 + (size_t)nrow * INs + k)
                                  : (Wh0 + (size_t)nrow * Hh + (k - INs));
      else        src = (k < Hh)  ? (Wx1 + (size_t)nrow * Hh + k)
                                  : (Wh1 + (size_t)nrow * Hh + (k - Hh));
      short8 v;
      #pragma unroll
      for (int j = 0; j < 8; ++j) v[j] = (short)f2bf(src[j]);
      const int slot = ((k8 >> 2) * 4 + (nl >> 4)) * 64 + ((k8 & 3) * 16 + (nl & 15));
      *(short8*)(smem + slot * 16) = v;
    }
  }
  {
    const float* bx = layer ? bx1 : bx0;
    const float* Wc = layer ? Wc1 : Wc0;
    if (tid < 64) bxl[tid] = bx[(tid >> 4) * Hh + j0 + (tid & 15)];
    if (tid < 48) wcl[tid] = Wc[(tid >> 4) * Hh + j0 + (tid & 15)];
  }
  __syncthreads();

  const int mrow = (wm << 5) + (lane & 15);
  const int koff = (lane >> 4) << 3;
  const int bg0  = (rb << 6) + mrow;      // global batch row (a0); a1 -> +16

  // ---- WG-private cell state in registers ----
  const int er = tid >> 2;   // unused name-compat; elementwise uses r3 q-loop
  (void)er;
  float cr0 = 0.f, cr1 = 0.f, cr2 = 0.f, cr3 = 0.f;

  for (int p = 0; p <= Tt; ++p) {
    const bool work = layer ? (p >= 1) : (p < Tt);
    if (work) {
      f32x4 zz = {0.f, 0.f, 0.f, 0.f};
      f32x4 acc00 = zz, acc01 = zz, acc10 = zz, acc11 = zz;
      const int bufR = (p - 1) & 1;

      if (!layer) {
        const int t = p;
        const unsigned short* hp0 = h0b + (size_t)bufR * (Bsz * Hh) + (size_t)bg0 * Hh + koff;
        const unsigned short* hp1 = hp0 + 16 * Hh;
        // x-part: ksteps 0..7, plain cached loads, fp32 -> bf16 on the fly
        const float* xp0 = x + ((size_t)bg0 * Tt + t) * INs + koff;
        const float* xp1 = xp0 + (size_t)16 * Tt * INs;
        #pragma unroll 2
        for (int ks = 0; ks < 8; ++ks) {
          const float* s0 = xp0 + ks * 32;
          const float* s1 = xp1 + ks * 32;
          short8 a0, a1;
          #pragma unroll
          for (int j = 0; j < 8; ++j) { a0[j] = (short)f2bf(s0[j]); a1[j] = (short)f2bf(s1[j]); }
          const char* bb = smem + (((ks << 2) + (wn << 1)) * 64 + lane) * 16;
          short8 b0v = *(const short8*)bb;
          short8 b1v = *(const short8*)(bb + 1024);
          MFMA4(a0, a1, b0v, b1v)
        }
        // h-part: ksteps 8..23, coherent atomic loads, 4-deep prefetch
        H_GEMM_HALF(hp0, hp1, 8)
      } else {
        // layer1, step t=p-1: gates = h0[t] @ Wx1^T + h1[t-1] @ Wh1^T
        const unsigned short* ap0 = h0b + (size_t)bufR * (Bsz * Hh) + (size_t)bg0 * Hh + koff;
        const unsigned short* ap1 = ap0 + 16 * Hh;
        H_GEMM_HALF(ap0, ap1, 0)
        const unsigned short* bp0 = h1b + (size_t)(p & 1) * (Bsz * Hh) + (size_t)bg0 * Hh + koff;
        const unsigned short* bp1 = bp0 + 16 * Hh;
        H_GEMM_HALF(bp0, bp1, 16)
      }

      // ---- stash gate tile to LDS (C-frag: row=(l>>4)*4+v, col=l&15) ----
      {
        const int r0 = (wm << 5) + ((lane >> 4) << 2);
        const int cA = (wn << 5) + (lane & 15);
        #pragma unroll
        for (int v = 0; v < 4; ++v) {
          gl[(r0 + v) * GL_STRIDE + cA]           = acc00[v];
          gl[(r0 + v) * GL_STRIDE + cA + 16]      = acc01[v];
          gl[(r0 + 16 + v) * GL_STRIDE + cA]      = acc10[v];
          gl[(r0 + 16 + v) * GL_STRIDE + cA + 16] = acc11[v];
        }
      }
      __syncthreads();

      // ---- fused peephole elementwise: 1024 cells, 4/thread (r3-exact) ----
      {
        unsigned short* hdst = layer ? (h1b + (size_t)((p - 1) & 1) * (Bsz * Hh))
                                     : (h0b + (size_t)(p & 1) * (Bsz * Hh));
        float cprev[4] = {cr0, cr1, cr2, cr3};
        float cnew[4];
        #pragma unroll
        for (int q = 0; q < 4; ++q) {
          const int cell = (q << 8) + tid;
          const int bl = cell >> 4, jj = cell & 15;
          const float* glr = gl + bl * GL_STRIDE + jj;
          float gi = glr[0]  + bxl[jj];
          float gf = glr[16] + bxl[16 + jj];
          float gg = glr[32] + bxl[32 + jj];
          float go = glr[48] + bxl[48 + jj];
          float co = cprev[q];
          float iv = sigf(gi + co * wcl[jj]);
          float fv = sigf(gf + co * wcl[16 + jj]);
          float gv = tanhf(gg);
          float cn = fv * co + iv * gv;
          float ov = sigf(go + cn * wcl[32 + jj]);
          cnew[q] = cn;
          const size_t sidx = (size_t)((rb << 6) + bl) * Hh + j0 + jj;
          unsigned short hv = f2bf(ov * tanhf(cn));
          __hip_atomic_store(hdst + sidx, hv, __ATOMIC_RELAXED, __HIP_MEMORY_SCOPE_AGENT);
        }
        cr0 = cnew[0]; cr1 = cnew[1]; cr2 = cnew[2]; cr3 = cnew[3];
      }
    }

    // ---- distributed flag barrier, NO per-phase acquire fence ----
    __syncthreads();   // drains vmcnt per-wave before s_barrier -> h stores done
    if (wave == 0) {
      const unsigned int tgt = (unsigned int)(p + 1);
      if (lane == 0)
        __hip_atomic_store(&flg[wg << 4], tgt, __ATOMIC_RELEASE, __HIP_MEMORY_SCOPE_AGENT);
      unsigned int* myf = &flg[((rb << 6) + lane) << 4];
      for (;;) {
        unsigned int v = AL(myf);
        if (__ballot(v >= tgt) == ~0ull) break;
        __builtin_amdgcn_s_sleep(2);
      }
    }
    __syncthreads();
  }

  // one-time acquire so plain cached loads below see final state
  __builtin_amdgcn_fence(__ATOMIC_ACQUIRE, "agent");

  // ---- final FC: out[wg][0..7] = h1_final[wg] @ Wfc^T + bfc ----
  const unsigned short* hf = h1b + (size_t)(Bsz * Hh);  // buffer 1 holds h1[127]
  float* red = (float*)smem;
  const int cc = tid & 7, ksl = tid >> 3;
  const unsigned short* hr = hf + (size_t)wg * Hh + ksl * 16;
  const float* wr = Wfc + (size_t)cc * Hh + ksl * 16;
  float s = 0.f;
  #pragma unroll
  for (int k = 0; k < 16; ++k) s += bf2f(hr[k]) * wr[k];
  red[tid] = s;
  __syncthreads();
  if (tid < 8) {
    float a = bfc[tid];
    #pragma unroll
    for (int i = 0; i < 32; ++i) a += red[i * 8 + tid];
    out[wg * 8 + tid] = a;
  }
}

extern "C" void kernel_launch(void* const* d_in, const int* in_sizes, int n_in,
                              void* d_out, int out_size, void* d_ws, size_t ws_size,
                              hipStream_t stream) {
  if (ws_size < (size_t)WS_ZERO_BYTES) return;

  const float* x   = (const float*)d_in[0];
  const float* Wx0 = (const float*)d_in[1];
  const float* bx0 = (const float*)d_in[2];
  const float* Wh0 = (const float*)d_in[3];
  const float* Wc0 = (const float*)d_in[4];
  const float* Wx1 = (const float*)d_in[5];
  const float* bx1 = (const float*)d_in[6];
  const float* Wh1 = (const float*)d_in[7];
  const float* Wc1 = (const float*)d_in[8];
  const float* Wfc = (const float*)d_in[9];
  const float* bfc = (const float*)d_in[10];
  float* out = (float*)d_out;
  unsigned char* ws = (unsigned char*)d_ws;

  (void)hipMemsetAsync(d_ws, 0, WS_ZERO_BYTES, stream);
  (void)hipFuncSetAttribute(reinterpret_cast<const void*>(lstm_fused),
                            hipFuncAttributeMaxDynamicSharedMemorySize, DYN_SHMEM);
  void* args[] = {&x, &Wx0, &bx0, &Wh0, &Wc0, &Wx1, &bx1, &Wh1, &Wc1, &Wfc, &bfc, &out, &ws};
  (void)hipLaunchCooperativeKernel((void*)lstm_fused, dim3(256), dim3(256), args,
                                   (unsigned int)DYN_SHMEM, stream);
}

// Round 7
// 2226.289 us; speedup vs baseline: 1.1639x; 1.1639x over previous
//
#include <hip/hip_runtime.h>
#include <stdint.h>

#define Bsz 256
#define Tt  128
#define INs 256
#define Hh  512

typedef __attribute__((ext_vector_type(8))) short short8;
typedef __attribute__((ext_vector_type(4))) float f32x4;

__device__ __forceinline__ unsigned short f2bf(float f) {
  union { float f; unsigned int u; } v; v.f = f;
  unsigned int u = v.u;
  u += 0x7FFFu + ((u >> 16) & 1u);   // round-to-nearest-even
  return (unsigned short)(u >> 16);
}
__device__ __forceinline__ float bf2f(unsigned short h) {
  union { unsigned int u; float f; } v; v.u = ((unsigned int)h) << 16;
  return v.f;
}
__device__ __forceinline__ float sigf(float x) { return 1.0f / (1.0f + expf(-x)); }

#define AL(P) __hip_atomic_load((P), __ATOMIC_RELAXED, __HIP_MEMORY_SCOPE_AGENT)

union Q2S { unsigned long long q[2]; short8 s; };

// ---- ws layout (bytes) ----
#define WS_FLAGS 0
#define WS_H0    16384
#define WS_H1    (WS_H0 + 2 * Bsz * Hh * 2)
#define WS_ZERO_BYTES (WS_H1 + 2 * Bsz * Hh * 2)   // 1065088

#define GL_STRIDE 65
#define W_BYTES   131072
#define GL_BYTES  (64 * GL_STRIDE * 4)             // 16640
#define BW_OFF    (W_BYTES + GL_BYTES)
#define DYN_SHMEM (BW_OFF + 64 * 4 + 48 * 4)       // 148160

#define MFMA4(A0, A1, B0, B1)                                                   \
  acc00 = __builtin_amdgcn_mfma_f32_16x16x32_bf16(A0, B0, acc00, 0, 0, 0);      \
  acc01 = __builtin_amdgcn_mfma_f32_16x16x32_bf16(A0, B1, acc01, 0, 0, 0);      \
  acc10 = __builtin_amdgcn_mfma_f32_16x16x32_bf16(A1, B0, acc10, 0, 0, 0);      \
  acc11 = __builtin_amdgcn_mfma_f32_16x16x32_bf16(A1, B1, acc11, 0, 0, 0);

// 8-deep prefetch pipeline over 16 ksteps of coherent h loads.
// PA/PB: row-block base pointers; KB: kstep base in LDS B layout.
#define H_GEMM_HALF(PA, PB, KB)                                                 \
  {                                                                             \
    unsigned long long pq[32];                                                  \
    _Pragma("unroll")                                                           \
    for (int s = 0; s < 8; ++s) {                                               \
      const unsigned long long* qa = (const unsigned long long*)((PA) + s * 32);\
      const unsigned long long* qb = (const unsigned long long*)((PB) + s * 32);\
      pq[s * 4 + 0] = AL(qa); pq[s * 4 + 1] = AL(qa + 1);                       \
      pq[s * 4 + 2] = AL(qb); pq[s * 4 + 3] = AL(qb + 1);                       \
    }                                                                           \
    _Pragma("unroll")                                                           \
    for (int ks = 0; ks < 16; ++ks) {                                           \
      const int sl = (ks & 7) << 2;                                             \
      Q2S ua, ub;                                                               \
      ua.q[0] = pq[sl + 0]; ua.q[1] = pq[sl + 1];                               \
      ub.q[0] = pq[sl + 2]; ub.q[1] = pq[sl + 3];                               \
      if (ks < 8) {                                                             \
        const unsigned long long* qa =                                          \
            (const unsigned long long*)((PA) + (ks + 8) * 32);                  \
        const unsigned long long* qb =                                          \
            (const unsigned long long*)((PB) + (ks + 8) * 32);                  \
        pq[sl + 0] = AL(qa); pq[sl + 1] = AL(qa + 1);                           \
        pq[sl + 2] = AL(qb); pq[sl + 3] = AL(qb + 1);                           \
      }                                                                         \
      const char* bb = smem + ((((ks + (KB)) << 2) + (wn << 1)) * 64 + lane) * 16; \
      short8 b0v = *(const short8*)bb;                                          \
      short8 b1v = *(const short8*)(bb + 1024);                                 \
      MFMA4(ua.s, ub.s, b0v, b1v)                                               \
    }                                                                           \
  }

extern "C" __global__ void __launch_bounds__(256)
lstm_fused(const float* __restrict__ x,
           const float* __restrict__ Wx0, const float* __restrict__ bx0,
           const float* __restrict__ Wh0, const float* __restrict__ Wc0,
           const float* __restrict__ Wx1, const float* __restrict__ bx1,
           const float* __restrict__ Wh1, const float* __restrict__ Wc1,
           const float* __restrict__ Wfc, const float* __restrict__ bfc,
           float* __restrict__ out, unsigned char* __restrict__ ws)
{
  extern __shared__ char smem[];
  unsigned int*   flg = (unsigned int*)(ws + WS_FLAGS);
  unsigned short* h0b = (unsigned short*)(ws + WS_H0);
  unsigned short* h1b = (unsigned short*)(ws + WS_H1);
  float* gl  = (float*)(smem + W_BYTES);
  float* bxl = (float*)(smem + BW_OFF);        // 64 floats: bias per local gate-col
  float* wcl = bxl + 64;                       // 48 floats: peephole weights

  const int wg    = blockIdx.x;
  const int rb    = wg >> 6;        // batch-row group (0..3), 64 rows each
  const int sub   = wg & 63;
  const int layer = sub >> 5;
  const int cb    = sub & 31;
  const int tid   = threadIdx.x;
  const int lane  = tid & 63;
  const int wave  = tid >> 6;
  const int wm    = wave >> 1, wn = wave & 1;
  const int j0    = cb << 4;

  // ---- preload this WG's weight slice into LDS, bf16, fragment order ----
  {
    const int K   = layer ? 1024 : 768;
    const int k8s = K >> 3;
    const int ng  = 64 * k8s;
    for (int idx = tid; idx < ng; idx += 256) {
      const int nl = idx / k8s;
      const int k8 = idx - nl * k8s;
      const int k  = k8 << 3;
      const int nrow = (nl >> 4) * Hh + j0 + (nl & 15);
      const float* src;
      if (!layer) src = (k < INs) ? (Wx0 + (size_t)nrow * INs + k)
                                  : (Wh0 + (size_t)nrow * Hh + (k - INs));
      else        src = (k < Hh)  ? (Wx1 + (size_t)nrow * Hh + k)
                                  : (Wh1 + (size_t)nrow * Hh + (k - Hh));
      short8 v;
      #pragma unroll
      for (int j = 0; j < 8; ++j) v[j] = (short)f2bf(src[j]);
      const int slot = ((k8 >> 2) * 4 + (nl >> 4)) * 64 + ((k8 & 3) * 16 + (nl & 15));
      *(short8*)(smem + slot * 16) = v;
    }
  }
  {
    const float* bx = layer ? bx1 : bx0;
    const float* Wc = layer ? Wc1 : Wc0;
    if (tid < 64) bxl[tid] = bx[(tid >> 4) * Hh + j0 + (tid & 15)];
    if (tid < 48) wcl[tid] = Wc[(tid >> 4) * Hh + j0 + (tid & 15)];
  }
  __syncthreads();

  const int mrow = (wm << 5) + (lane & 15);
  const int koff = (lane >> 4) << 3;
  const int bg0  = (rb << 6) + mrow;      // global batch row (a0); a1 -> +16

  // ---- WG-private cell state in registers ----
  float cr0 = 0.f, cr1 = 0.f, cr2 = 0.f, cr3 = 0.f;

  for (int p = 0; p <= Tt; ++p) {
    const bool work = layer ? (p >= 1) : (p < Tt);
    if (work) {
      f32x4 zz = {0.f, 0.f, 0.f, 0.f};
      f32x4 acc00 = zz, acc01 = zz, acc10 = zz, acc11 = zz;
      const int bufR = (p - 1) & 1;

      if (!layer) {
        const int t = p;
        const unsigned short* hp0 = h0b + (size_t)bufR * (Bsz * Hh) + (size_t)bg0 * Hh + koff;
        const unsigned short* hp1 = hp0 + 16 * Hh;
        // x-part: ksteps 0..7, plain cached loads, fp32 -> bf16 on the fly
        const float* xp0 = x + ((size_t)bg0 * Tt + t) * INs + koff;
        const float* xp1 = xp0 + (size_t)16 * Tt * INs;
        #pragma unroll 2
        for (int ks = 0; ks < 8; ++ks) {
          const float* s0 = xp0 + ks * 32;
          const float* s1 = xp1 + ks * 32;
          short8 a0, a1;
          #pragma unroll
          for (int j = 0; j < 8; ++j) { a0[j] = (short)f2bf(s0[j]); a1[j] = (short)f2bf(s1[j]); }
          const char* bb = smem + (((ks << 2) + (wn << 1)) * 64 + lane) * 16;
          short8 b0v = *(const short8*)bb;
          short8 b1v = *(const short8*)(bb + 1024);
          MFMA4(a0, a1, b0v, b1v)
        }
        // h-part: ksteps 8..23, coherent atomic loads, 8-deep prefetch
        H_GEMM_HALF(hp0, hp1, 8)
      } else {
        // layer1, step t=p-1: gates = h0[t] @ Wx1^T + h1[t-1] @ Wh1^T
        const unsigned short* ap0 = h0b + (size_t)bufR * (Bsz * Hh) + (size_t)bg0 * Hh + koff;
        const unsigned short* ap1 = ap0 + 16 * Hh;
        H_GEMM_HALF(ap0, ap1, 0)
        const unsigned short* bp0 = h1b + (size_t)(p & 1) * (Bsz * Hh) + (size_t)bg0 * Hh + koff;
        const unsigned short* bp1 = bp0 + 16 * Hh;
        H_GEMM_HALF(bp0, bp1, 16)
      }

      // ---- stash gate tile to LDS (C-frag: row=(l>>4)*4+v, col=l&15) ----
      {
        const int r0 = (wm << 5) + ((lane >> 4) << 2);
        const int cA = (wn << 5) + (lane & 15);
        #pragma unroll
        for (int v = 0; v < 4; ++v) {
          gl[(r0 + v) * GL_STRIDE + cA]           = acc00[v];
          gl[(r0 + v) * GL_STRIDE + cA + 16]      = acc01[v];
          gl[(r0 + 16 + v) * GL_STRIDE + cA]      = acc10[v];
          gl[(r0 + 16 + v) * GL_STRIDE + cA + 16] = acc11[v];
        }
      }
      __syncthreads();

      // ---- fused peephole elementwise: 1024 cells, 4/thread ----
      {
        unsigned short* hdst = layer ? (h1b + (size_t)((p - 1) & 1) * (Bsz * Hh))
                                     : (h0b + (size_t)(p & 1) * (Bsz * Hh));
        float cprev[4] = {cr0, cr1, cr2, cr3};
        float cnew[4];
        #pragma unroll
        for (int q = 0; q < 4; ++q) {
          const int cell = (q << 8) + tid;
          const int bl = cell >> 4, jj = cell & 15;
          const float* glr = gl + bl * GL_STRIDE + jj;
          float gi = glr[0]  + bxl[jj];
          float gf = glr[16] + bxl[16 + jj];
          float gg = glr[32] + bxl[32 + jj];
          float go = glr[48] + bxl[48 + jj];
          float co = cprev[q];
          float iv = sigf(gi + co * wcl[jj]);
          float fv = sigf(gf + co * wcl[16 + jj]);
          float gv = tanhf(gg);
          float cn = fv * co + iv * gv;
          float ov = sigf(go + cn * wcl[32 + jj]);
          cnew[q] = cn;
          const size_t sidx = (size_t)((rb << 6) + bl) * Hh + j0 + jj;
          unsigned short hv = f2bf(ov * tanhf(cn));
          __hip_atomic_store(hdst + sidx, hv, __ATOMIC_RELAXED, __HIP_MEMORY_SCOPE_AGENT);
        }
        cr0 = cnew[0]; cr1 = cnew[1]; cr2 = cnew[2]; cr3 = cnew[3];
      }
    }

    // ---- distributed flag barrier, RELAXED flag store (no wbl2 on crit path):
    //      h stores are sc0sc1 agent-atomics, drained by the vmcnt(0) the
    //      compiler emits before s_barrier -> already globally visible when
    //      the flag store issues. ----
    __syncthreads();
    if (wave == 0) {
      const unsigned int tgt = (unsigned int)(p + 1);
      if (lane == 0)
        __hip_atomic_store(&flg[wg << 4], tgt, __ATOMIC_RELAXED, __HIP_MEMORY_SCOPE_AGENT);
      unsigned int* myf = &flg[((rb << 6) + lane) << 4];
      for (;;) {
        unsigned int v = AL(myf);
        if (__ballot(v >= tgt) == ~0ull) break;
        __builtin_amdgcn_s_sleep(2);
      }
    }
    __syncthreads();
  }

  // one-time acquire so plain cached loads below see final state
  __builtin_amdgcn_fence(__ATOMIC_ACQUIRE, "agent");

  // ---- final FC: out[wg][0..7] = h1_final[wg] @ Wfc^T + bfc ----
  const unsigned short* hf = h1b + (size_t)(Bsz * Hh);  // buffer 1 holds h1[127]
  float* red = (float*)smem;
  const int cc = tid & 7, ksl = tid >> 3;
  const unsigned short* hr = hf + (size_t)wg * Hh + ksl * 16;
  const float* wr = Wfc + (size_t)cc * Hh + ksl * 16;
  float s = 0.f;
  #pragma unroll
  for (int k = 0; k < 16; ++k) s += bf2f(hr[k]) * wr[k];
  red[tid] = s;
  __syncthreads();
  if (tid < 8) {
    float a = bfc[tid];
    #pragma unroll
    for (int i = 0; i < 32; ++i) a += red[i * 8 + tid];
    out[wg * 8 + tid] = a;
  }
}

extern "C" void kernel_launch(void* const* d_in, const int* in_sizes, int n_in,
                              void* d_out, int out_size, void* d_ws, size_t ws_size,
                              hipStream_t stream) {
  if (ws_size < (size_t)WS_ZERO_BYTES) return;

  const float* x   = (const float*)d_in[0];
  const float* Wx0 = (const float*)d_in[1];
  const float* bx0 = (const float*)d_in[2];
  const float* Wh0 = (const float*)d_in[3];
  const float* Wc0 = (const float*)d_in[4];
  const float* Wx1 = (const float*)d_in[5];
  const float* bx1 = (const float*)d_in[6];
  const float* Wh1 = (const float*)d_in[7];
  const float* Wc1 = (const float*)d_in[8];
  const float* Wfc = (const float*)d_in[9];
  const float* bfc = (const float*)d_in[10];
  float* out = (float*)d_out;
  unsigned char* ws = (unsigned char*)d_ws;

  (void)hipMemsetAsync(d_ws, 0, WS_ZERO_BYTES, stream);
  (void)hipFuncSetAttribute(reinterpret_cast<const void*>(lstm_fused),
                            hipFuncAttributeMaxDynamicSharedMemorySize, DYN_SHMEM);
  void* args[] = {&x, &Wx0, &bx0, &Wh0, &Wc0, &Wx1, &bx1, &Wh1, &Wc1, &Wfc, &bfc, &out, &ws};
  (void)hipLaunchCooperativeKernel((void*)lstm_fused, dim3(256), dim3(256), args,
                                   (unsigned int)DYN_SHMEM, stream);
}

// Round 8
// 1258.499 us; speedup vs baseline: 2.0589x; 1.7690x over previous
//
#include <hip/hip_runtime.h>
#include <stdint.h>

#define Bsz 256
#define Tt  128
#define INs 256
#define Hh  512

typedef __attribute__((ext_vector_type(8))) short short8;
typedef __attribute__((ext_vector_type(4))) float f32x4;

__device__ __forceinline__ unsigned short f2bf(float f) {
  union { float f; unsigned int u; } v; v.f = f;
  unsigned int u = v.u;
  u += 0x7FFFu + ((u >> 16) & 1u);   // round-to-nearest-even
  return (unsigned short)(u >> 16);
}
__device__ __forceinline__ float bf2f(unsigned short h) {
  union { unsigned int u; float f; } v; v.u = ((unsigned int)h) << 16;
  return v.f;
}
__device__ __forceinline__ float sigf(float x) { return 1.0f / (1.0f + expf(-x)); }

#define AL(P) __hip_atomic_load((P), __ATOMIC_RELAXED, __HIP_MEMORY_SCOPE_AGENT)

union Q2S { unsigned long long q[2]; short8 s; };

// ---- ws layout (bytes) ----
#define WS_F0 0
#define WS_F1 8192
#define WS_H0 16384                          // 4 ring slots x 256 KB
#define WS_H1 (WS_H0 + 4 * Bsz * Hh * 2)     // 2 ring slots x 256 KB
#define WS_ZERO_BYTES (WS_H1 + 2 * Bsz * Hh * 2)   // 1589248

#define W_BYTES   131072
#define DYN_SHMEM (W_BYTES + 64 * 4 + 48 * 4)

// poll all 32 flags of a group (64 lanes, each flag checked twice)
#define POLLGE(BASE, TGT)                                                       \
  if ((TGT) > 0) {                                                              \
    const int* fp_ = (BASE) + ((lane & 31) << 4);                               \
    for (;;) {                                                                  \
      int v_ = AL(fp_);                                                         \
      if (__ballot(v_ >= (TGT)) == ~0ull) break;                                \
      __builtin_amdgcn_s_sleep(2);                                              \
    }                                                                           \
  }

// 16 ksteps of h-GEMM over one 16-row A set, 8-deep coherent prefetch.
// PA: per-lane row base (+koff). KB: kstep base in LDS B layout.
#define H_GEMM(PA, KB)                                                          \
  {                                                                             \
    unsigned long long pq[16];                                                  \
    _Pragma("unroll")                                                           \
    for (int s = 0; s < 8; ++s) {                                               \
      const unsigned long long* qa = (const unsigned long long*)((PA) + s * 32);\
      pq[s * 2] = AL(qa); pq[s * 2 + 1] = AL(qa + 1);                           \
    }                                                                           \
    _Pragma("unroll")                                                           \
    for (int ks = 0; ks < 16; ++ks) {                                           \
      const int sl = (ks & 7) << 1;                                             \
      Q2S u; u.q[0] = pq[sl]; u.q[1] = pq[sl + 1];                              \
      if (ks < 8) {                                                             \
        const unsigned long long* qa =                                          \
            (const unsigned long long*)((PA) + (ks + 8) * 32);                  \
        pq[sl] = AL(qa); pq[sl + 1] = AL(qa + 1);                               \
      }                                                                         \
      _Pragma("unroll")                                                         \
      for (int c4 = 0; c4 < 4; ++c4) {                                          \
        short8 b = *(const short8*)(smem + (((ks + (KB)) * 4 + c4) * 64 + lane) * 16); \
        acc[c4] = __builtin_amdgcn_mfma_f32_16x16x32_bf16(u.s, b, acc[c4], 0, 0, 0);   \
      }                                                                         \
    }                                                                           \
  }

// in-register peephole elementwise for one lane's 4 cells + h store
#define ELEMWISE(HDST)                                                          \
  {                                                                             \
    const int jj = lane & 15;                                                   \
    _Pragma("unroll")                                                           \
    for (int v = 0; v < 4; ++v) {                                               \
      const int R = (wave << 4) + ((lane >> 4) << 2) + v;                       \
      float gi = acc[0][v] + bxl[jj];                                           \
      float gf = acc[1][v] + bxl[16 + jj];                                      \
      float gg = acc[2][v] + bxl[32 + jj];                                      \
      float go = acc[3][v] + bxl[48 + jj];                                      \
      float co = cr[v];                                                         \
      float iv = sigf(gi + co * wcl[jj]);                                       \
      float fv = sigf(gf + co * wcl[16 + jj]);                                  \
      float gv = tanhf(gg);                                                     \
      float cn = fv * co + iv * gv;                                             \
      float ov = sigf(go + cn * wcl[32 + jj]);                                  \
      cr[v] = cn;                                                               \
      __hip_atomic_store((HDST) + (size_t)((g << 6) + R) * Hh + j0 + jj,        \
                         f2bf(ov * tanhf(cn)),                                  \
                         __ATOMIC_RELAXED, __HIP_MEMORY_SCOPE_AGENT);           \
    }                                                                           \
  }

extern "C" __global__ void __launch_bounds__(256)
lstm_fused(const float* __restrict__ x,
           const float* __restrict__ Wx0, const float* __restrict__ bx0,
           const float* __restrict__ Wh0, const float* __restrict__ Wc0,
           const float* __restrict__ Wx1, const float* __restrict__ bx1,
           const float* __restrict__ Wh1, const float* __restrict__ Wc1,
           const float* __restrict__ Wfc, const float* __restrict__ bfc,
           float* __restrict__ out, unsigned char* __restrict__ ws)
{
  extern __shared__ char smem[];
  unsigned short* h0b = (unsigned short*)(ws + WS_H0);
  unsigned short* h1b = (unsigned short*)(ws + WS_H1);
  float* bxl = (float*)(smem + W_BYTES);     // 64 floats: bias per local gate-col
  float* wcl = bxl + 64;                     // 48 floats: peephole weights

  const int wg    = blockIdx.x;
  const int g     = wg >> 6;        // batch-row group (0..3), 64 rows each
  const int sub   = wg & 63;
  const int layer = sub >> 5;
  const int cb    = sub & 31;       // 16 hidden cols
  const int tid   = threadIdx.x;
  const int lane  = tid & 63;
  const int wave  = tid >> 6;
  const int j0    = cb << 4;

  int* f0base = (int*)(ws + WS_F0) + (g << 9);     // 32 flags x 16-int stride
  int* f1base = (int*)(ws + WS_F1) + (g << 9);
  int* myflag = (layer ? f1base : f0base) + (cb << 4);

  // ---- preload this WG's weight slice into LDS, bf16, fragment order ----
  {
    const int K   = layer ? 1024 : 768;
    const int k8s = K >> 3;
    const int ng  = 64 * k8s;
    for (int idx = tid; idx < ng; idx += 256) {
      const int nl = idx / k8s;
      const int k8 = idx - nl * k8s;
      const int k  = k8 << 3;
      const int nrow = (nl >> 4) * Hh + j0 + (nl & 15);
      const float* src;
      if (!layer) src = (k < INs) ? (Wx0 + (size_t)nrow * INs + k)
                                  : (Wh0 + (size_t)nrow * Hh + (k - INs));
      else        src = (k < Hh)  ? (Wx1 + (size_t)nrow * Hh + k)
                                  : (Wh1 + (size_t)nrow * Hh + (k - Hh));
      short8 v;
      #pragma unroll
      for (int j = 0; j < 8; ++j) v[j] = (short)f2bf(src[j]);
      const int slot = ((k8 >> 2) * 4 + (nl >> 4)) * 64 + ((k8 & 3) * 16 + (nl & 15));
      *(short8*)(smem + slot * 16) = v;
    }
  }
  {
    const float* bx = layer ? bx1 : bx0;
    const float* Wc = layer ? Wc1 : Wc0;
    if (tid < 64) bxl[tid] = bx[(tid >> 4) * Hh + j0 + (tid & 15)];
    if (tid < 48) wcl[tid] = Wc[(tid >> 4) * Hh + j0 + (tid & 15)];
  }
  __syncthreads();

  // ---- wave tile: 16 rows x 64 gate-cols; lane -> A row (lane&15), k-off ----
  const int lr   = (wave << 4) + (lane & 15);   // local row 0..63
  const int koff = (lane >> 4) << 3;            // shorts
  const int bg   = (g << 6) + lr;               // global batch row

  float cr[4] = {0.f, 0.f, 0.f, 0.f};          // cell state (4 rows x 1 col per lane)
  const f32x4 zz = {0.f, 0.f, 0.f, 0.f};

  if (!layer) {
    // =============== LAYER 0: runs ahead on 4-deep h0 ring ===============
    for (int t = 0; t < Tt; ++t) {
      f32x4 acc[4] = {zz, zz, zz, zz};
      // x-part FIRST (independent of peers) -> overlaps flag propagation
      const float* xp = x + ((size_t)bg * Tt + t) * INs + koff;
      #pragma unroll 2
      for (int ks = 0; ks < 8; ++ks) {
        const float* s0 = xp + ks * 32;
        short8 a;
        #pragma unroll
        for (int j = 0; j < 8; ++j) a[j] = (short)f2bf(s0[j]);
        #pragma unroll
        for (int c4 = 0; c4 < 4; ++c4) {
          short8 b = *(const short8*)(smem + ((ks * 4 + c4) * 64 + lane) * 16);
          acc[c4] = __builtin_amdgcn_mfma_f32_16x16x32_bf16(a, b, acc[c4], 0, 0, 0);
        }
      }
      POLLGE(f0base, t)       // peers' h0[t-1] written
      POLLGE(f1base, t - 3)   // ring slot t&3 consumed by layer1
      const unsigned short* hp = h0b + (size_t)((t + 3) & 3) * (Bsz * Hh)
                                     + (size_t)bg * Hh + koff;   // slot (t-1)&3
      H_GEMM(hp, 8)
      unsigned short* hdst = h0b + (size_t)(t & 3) * (Bsz * Hh);
      ELEMWISE(hdst)
      __syncthreads();        // drains vmcnt -> h stores globally visible
      if (tid == 0)
        __hip_atomic_store(myflag, t + 1, __ATOMIC_RELAXED, __HIP_MEMORY_SCOPE_AGENT);
    }
  } else {
    // =============== LAYER 1: trails layer 0 ===============
    for (int u = 0; u < Tt; ++u) {
      f32x4 acc[4] = {zz, zz, zz, zz};
      POLLGE(f1base, u)       // peers' h1[u-1] written
      const unsigned short* bp = h1b + (size_t)((u + 1) & 1) * (Bsz * Hh)
                                     + (size_t)bg * Hh + koff;   // slot (u-1)&1
      H_GEMM(bp, 16)          // h1 @ Wh1 half (ksteps 16..31)
      POLLGE(f0base, u + 1)   // layer0's h0[u] written
      const unsigned short* ap = h0b + (size_t)(u & 3) * (Bsz * Hh)
                                     + (size_t)bg * Hh + koff;
      H_GEMM(ap, 0)           // h0 @ Wx1 half (ksteps 0..15)
      unsigned short* hdst = h1b + (size_t)(u & 1) * (Bsz * Hh);
      ELEMWISE(hdst)
      __syncthreads();
      if (tid == 0)
        __hip_atomic_store(myflag, u + 1, __ATOMIC_RELAXED, __HIP_MEMORY_SCOPE_AGENT);
    }
  }

  // ---- wait for my output row's group to finish layer 1 ----
  {
    const int og = wg >> 6;
    int* f1o = (int*)(ws + WS_F1) + (og << 9);
    POLLGE(f1o, Tt)
  }
  __builtin_amdgcn_fence(__ATOMIC_ACQUIRE, "agent");
  __builtin_amdgcn_sched_barrier(0);

  // ---- final FC: out[wg][0..7] = h1_final[wg] @ Wfc^T + bfc ----
  const unsigned short* hf = h1b + (size_t)(Bsz * Hh);  // slot 1 holds h1[127]
  float* red = (float*)smem;
  const int cc = tid & 7, ksl = tid >> 3;
  const unsigned short* hr = hf + (size_t)wg * Hh + ksl * 16;
  const float* wr = Wfc + (size_t)cc * Hh + ksl * 16;
  float s = 0.f;
  #pragma unroll
  for (int k = 0; k < 16; ++k) s += bf2f(hr[k]) * wr[k];
  __syncthreads();           // everyone past weight reads before smem reuse
  red[tid] = s;
  __syncthreads();
  if (tid < 8) {
    float a = bfc[tid];
    #pragma unroll
    for (int i = 0; i < 32; ++i) a += red[i * 8 + tid];
    out[wg * 8 + tid] = a;
  }
}

extern "C" void kernel_launch(void* const* d_in, const int* in_sizes, int n_in,
                              void* d_out, int out_size, void* d_ws, size_t ws_size,
                              hipStream_t stream) {
  if (ws_size < (size_t)WS_ZERO_BYTES) return;

  const float* x   = (const float*)d_in[0];
  const float* Wx0 = (const float*)d_in[1];
  const float* bx0 = (const float*)d_in[2];
  const float* Wh0 = (const float*)d_in[3];
  const float* Wc0 = (const float*)d_in[4];
  const float* Wx1 = (const float*)d_in[5];
  const float* bx1 = (const float*)d_in[6];
  const float* Wh1 = (const float*)d_in[7];
  const float* Wc1 = (const float*)d_in[8];
  const float* Wfc = (const float*)d_in[9];
  const float* bfc = (const float*)d_in[10];
  float* out = (float*)d_out;
  unsigned char* ws = (unsigned char*)d_ws;

  (void)hipMemsetAsync(d_ws, 0, WS_ZERO_BYTES, stream);
  (void)hipFuncSetAttribute(reinterpret_cast<const void*>(lstm_fused),
                            hipFuncAttributeMaxDynamicSharedMemorySize, DYN_SHMEM);
  void* args[] = {&x, &Wx0, &bx0, &Wh0, &Wc0, &Wx1, &bx1, &Wh1, &Wc1, &Wfc, &bfc, &out, &ws};
  (void)hipLaunchCooperativeKernel((void*)lstm_fused, dim3(256), dim3(256), args,
                                   (unsigned int)DYN_SHMEM, stream);
}